// Round 6
// baseline (293.238 us; speedup 1.0000x reference)
//
#include <hip/hip_runtime.h>
#include <hip/hip_bf16.h>
#include <stdint.h>

typedef __bf16 bf16x8 __attribute__((ext_vector_type(8)));
typedef __bf16 bf16x4 __attribute__((ext_vector_type(4)));
typedef float f32x4 __attribute__((ext_vector_type(4)));

#define B_ 2
#define LQ_ 2048
#define LK_ 2048
#define NH_ 16
#define DH_ 64
#define DM_ 1024
#define NKT_ (LK_ / 64)

#define AS1 __attribute__((address_space(1)))
#define AS3 __attribute__((address_space(3)))

__device__ __forceinline__ void gload_lds16(const void* g, void* l) {
  __builtin_amdgcn_global_load_lds((const AS1 uint32_t*)g, (AS3 uint32_t*)l, 16, 0, 0);
}

// Pack mask (B,LQ,LK) int32 -> bitmask (1 bit/elem).
__global__ __launch_bounds__(256) void pack_mask_kernel(
    const int* __restrict__ m, unsigned* __restrict__ out) {
  int gtid = blockIdx.x * 256 + threadIdx.x;
  unsigned long long bal = __ballot(m[gtid] != 0);
  if ((threadIdx.x & 31) == 0)
    out[gtid >> 5] = (unsigned)(bal >> ((threadIdx.x & 32) ? 32 : 0));
}

// One kernel converting q,k,v (4.19M ea) and Wq,Wk,Wv (1.05M ea) fp32->bf16.
__global__ __launch_bounds__(256) void cvt6_kernel(
    const float* __restrict__ q, const float* __restrict__ k,
    const float* __restrict__ v, const float* __restrict__ wq,
    const float* __restrict__ wk, const float* __restrict__ wv,
    __bf16* __restrict__ X0, __bf16* __restrict__ X1, __bf16* __restrict__ X2,
    __bf16* __restrict__ W0, __bf16* __restrict__ W1, __bf16* __restrict__ W2) {
  int seg = blockIdx.y;
  if (seg >= 3 && blockIdx.x >= DM_ * DM_ / 1024) return;
  const float* s = seg == 0 ? q : seg == 1 ? k : seg == 2 ? v
                  : seg == 3 ? wq : seg == 4 ? wk : wv;
  __bf16* d = seg == 0 ? X0 : seg == 1 ? X1 : seg == 2 ? X2
             : seg == 3 ? W0 : seg == 4 ? W1 : W2;
  size_t t = (size_t)blockIdx.x * 256 + threadIdx.x;
  float4 f = ((const float4*)s)[t];
  bf16x4 o;
  o[0] = (__bf16)f.x; o[1] = (__bf16)f.y; o[2] = (__bf16)f.z; o[3] = (__bf16)f.w;
  ((bf16x4*)d)[t] = o;
}

// GEMM C = X @ W^T + bias, 128x128 tile, BK=32, DOUBLE-BUFFERED staging
// (stage k+1 right after the barrier, compute k -> one barrier per K-step).
// All LDS unioned into 32 KB. mode=blockIdx.z: 0=q(std), 1=k(std+T), 2=v(T).
// Tiled-T layout: T[bh][kti][d(64)][kl(64)].
__global__ __launch_bounds__(256) void proj_kernel(
    const __bf16* __restrict__ X0, const __bf16* __restrict__ X1,
    const __bf16* __restrict__ X2,
    const float* __restrict__ b0p, const float* __restrict__ b1p,
    const float* __restrict__ b2p,
    const __bf16* __restrict__ W0, const __bf16* __restrict__ W1,
    const __bf16* __restrict__ W2,
    __bf16* __restrict__ qh, __bf16* __restrict__ kh,
    __bf16* __restrict__ khT, __bf16* __restrict__ vhT) {
  // smem[sel][0]=A-tile, smem[sel][1]=B-tile (16 KB per sel); cbuf aliases all.
  __shared__ __align__(16) __bf16 smem[2][2][128 * 32];
  __bf16* cbuf = &smem[0][0][0];  // epilogue only (18 KB < 32 KB)

  const int mode = blockIdx.z;
  const __bf16* X = mode == 0 ? X0 : (mode == 1 ? X1 : X2);
  const __bf16* W = mode == 0 ? W0 : (mode == 1 ? W1 : W2);
  const float* bias = mode == 0 ? b0p : (mode == 1 ? b1p : b2p);
  __bf16* ostd = mode == 0 ? qh : (mode == 1 ? kh : nullptr);
  __bf16* otr = mode == 0 ? nullptr : (mode == 1 ? khT : vhT);

  const int t = threadIdx.x;
  const int wave = t >> 6, lane = t & 63;
  const int lo16 = lane & 15, quad = lane >> 4;
  const int wm = wave >> 1, wn = wave & 1;
  const int m0 = blockIdx.x * 128, n0 = blockIdx.y * 128;
  const int srow = lane >> 2, scg = (lane & 3) ^ (srow & 3);  // XOR chunk swizzle

  f32x4 acc[4][4] = {};

  auto stage = [&](int k0, int sel) {
#pragma unroll
    for (int ii = 2 * wave; ii < 2 * wave + 2; ii++) {
      int row = ii * 16 + srow;
      gload_lds16(X + (size_t)(m0 + row) * DM_ + k0 + scg * 8, &smem[sel][0][ii * 512]);
      gload_lds16(W + (size_t)(n0 + row) * DM_ + k0 + scg * 8, &smem[sel][1][ii * 512]);
    }
  };

  stage(0, 0);
  for (int k0 = 0; k0 < DM_; k0 += 32) {
    const int sel = (k0 >> 5) & 1;
    __syncthreads();
    if (k0 + 32 < DM_) stage(k0 + 32, sel ^ 1);
    bf16x8 af[4], bfr[4];
#pragma unroll
    for (int g = 0; g < 4; g++) {
      int ar = wm * 64 + g * 16 + lo16;
      af[g] = *(const bf16x8*)(&smem[sel][0][ar * 32 + (quad ^ (ar & 3)) * 8]);
      int br = wn * 64 + g * 16 + lo16;
      bfr[g] = *(const bf16x8*)(&smem[sel][1][br * 32 + (quad ^ (br & 3)) * 8]);
    }
#pragma unroll
    for (int gm = 0; gm < 4; gm++)
#pragma unroll
      for (int gn = 0; gn < 4; gn++)
        acc[gm][gn] =
            __builtin_amdgcn_mfma_f32_16x16x32_bf16(af[gm], bfr[gn], acc[gm][gn], 0, 0, 0);
  }

  const int b = m0 >> 11, l0 = m0 & 2047;
  for (int nhf = 0; nhf < 2; nhf++) {
    int h = (n0 >> 6) + nhf;
    int bh = b * NH_ + h;
    if (ostd) {
      __syncthreads();
      if (wn == nhf) {
#pragma unroll
        for (int gn = 0; gn < 4; gn++) {
          float bi = bias[n0 + nhf * 64 + gn * 16 + lo16];
#pragma unroll
          for (int gm = 0; gm < 4; gm++)
#pragma unroll
            for (int r = 0; r < 4; r++)
              cbuf[(wm * 64 + gm * 16 + quad * 4 + r) * 72 + gn * 16 + lo16] =
                  (__bf16)(acc[gm][gn][r] + bi);
        }
      }
      __syncthreads();
      int m = t >> 1, coff = (t & 1) * 32;
      __bf16* dst = ostd + ((size_t)bh * LQ_ + l0 + m) * DH_ + coff;
#pragma unroll
      for (int j = 0; j < 4; j++)
        *(bf16x8*)(dst + j * 8) = *(const bf16x8*)&cbuf[m * 72 + coff + j * 8];
    }
    if (otr) {
      __syncthreads();
      if (wn == nhf) {
#pragma unroll
        for (int gn = 0; gn < 4; gn++) {
          float bi = bias[n0 + nhf * 64 + gn * 16 + lo16];
#pragma unroll
          for (int gm = 0; gm < 4; gm++) {
            bf16x4 pk;
#pragma unroll
            for (int r = 0; r < 4; r++) pk[r] = (__bf16)(acc[gm][gn][r] + bi);
            *(bf16x4*)&cbuf[(gn * 16 + lo16) * 136 + wm * 64 + gm * 16 + quad * 4] = pk;
          }
        }
      }
      __syncthreads();
      int d = t >> 2, mc = (t & 3) * 32;
      int kti = (l0 + mc) >> 6, kl = (l0 + mc) & 63;
      __bf16* dst = otr + ((size_t)(bh * NKT_ + kti) * 64 + d) * 64 + kl;
#pragma unroll
      for (int j = 0; j < 4; j++)
        *(bf16x8*)(dst + j * 8) = *(const bf16x8*)&cbuf[d * 136 + mc + j * 8];
    }
  }
}

// Flash attention v3: computes S^T = K Q^T (swapped MFMA operands -> lane owns
// q=lo16, keys=gg*16+quad*4+r). The C->A layout transform for P is then a pure
// quad-permute done with 16 __shfl + 8 selects — NO LDS round-trip, no p_lds.
// LDS = 48 KB (3 staging dbufs) -> 3 blocks/CU. Double-buffered staging, one
// barrier/tile. blockIdx.x = bh -> XCD L2 locality.
__global__ __launch_bounds__(256, 3) void attn_kernel(
    const __bf16* __restrict__ qh, const __bf16* __restrict__ kh,
    const __bf16* __restrict__ khT, const __bf16* __restrict__ vhT,
    const unsigned* __restrict__ maskp,
    float* __restrict__ out_k, float* __restrict__ out_v) {
  __shared__ __align__(16) __bf16 kbuf[2][64 * 64];
  __shared__ __align__(16) __bf16 ktbuf[2][64 * 64];
  __shared__ __align__(16) __bf16 vtbuf[2][64 * 64];

  const int t = threadIdx.x;
  const int wave = t >> 6, lane = t & 63;
  const int lo16 = lane & 15, quad = lane >> 4;
  const int bh = blockIdx.x;
  const int b = bh >> 4, h = bh & 15;
  const int q0 = blockIdx.y * 64 + wave * 16;
  const int srow = lane >> 3;
  const int scg = (lane & 7) ^ srow;  // XOR chunk swizzle
  const int rsw = lo16 & 7;           // read-side row & 7

  const __bf16* qrow = qh + ((size_t)bh * LQ_ + q0 + lo16) * DH_ + quad * 8;
  bf16x8 a_q0 = *(const bf16x8*)(qrow);        // B-frag: n=q, k=d 0..31
  bf16x8 a_q1 = *(const bf16x8*)(qrow + 32);   // k=d 32..63

  f32x4 acc_v[4] = {};
  f32x4 acc_k[4] = {};
  float lsum = 0.f;

  const __bf16* khb = kh + (size_t)bh * LK_ * DH_;
  const __bf16* ktb = khT + (size_t)bh * LK_ * DH_;
  const __bf16* vtb = vhT + (size_t)bh * LK_ * DH_;
  const unsigned* mb = maskp + ((size_t)b * LQ_ + q0 + lo16) * (LK_ / 32);

  auto stage = [&](int kti, int sel) {
    const int tb = kti * 4096;
#pragma unroll
    for (int ii = 2 * wave; ii < 2 * wave + 2; ii++) {
      int row = ii * 8 + srow;
      gload_lds16(khb + (size_t)(kti * 64 + row) * DH_ + scg * 8, &kbuf[sel][ii * 512]);
      gload_lds16(ktb + tb + row * 64 + scg * 8, &ktbuf[sel][ii * 512]);
      gload_lds16(vtb + tb + row * 64 + scg * 8, &vtbuf[sel][ii * 512]);
    }
  };

  stage(0, 0);
  for (int kti = 0; kti < NKT_; kti++) {
    const int cur = kti & 1;
    __syncthreads();  // drains stage(cur), issued a full compute-phase ago
    if (kti + 1 < NKT_) stage(kti + 1, cur ^ 1);

    // ---- S^T = K Q^T : A = K-frag (m=key), B = Q-frag (n=q) ----
    f32x4 s[4];
#pragma unroll
    for (int gg = 0; gg < 4; gg++) {
      int row = gg * 16 + lo16;  // key row in kbuf
      bf16x8 ka0 = *(const bf16x8*)(&kbuf[cur][row * 64 + ((quad ^ rsw) * 8)]);
      bf16x8 ka1 = *(const bf16x8*)(&kbuf[cur][row * 64 + (((quad + 4) ^ rsw) * 8)]);
      f32x4 z = {};
      z = __builtin_amdgcn_mfma_f32_16x16x32_bf16(ka0, a_q0, z, 0, 0, 0);
      z = __builtin_amdgcn_mfma_f32_16x16x32_bf16(ka1, a_q1, z, 0, 0, 0);
      s[gg] = z;  // s[gg][r] = S[q=lo16][key=gg*16+quad*4+r]
    }
    // ---- mask + exp (fixed max = 0); lane's q row = lo16 -> 2 mask words ----
    unsigned mw0 = mb[kti * 2], mw1 = mb[kti * 2 + 1];
#pragma unroll
    for (int gg = 0; gg < 4; gg++) {
      unsigned w = (gg < 2) ? mw0 : mw1;
      int bitbase = (gg & 1) * 16 + quad * 4;
#pragma unroll
      for (int r = 0; r < 4; r++) {
        float arg = ((w >> (bitbase + r)) & 1) ? s[gg][r] * 0.125f : -28.0f;
        float p = __expf(arg);
        s[gg][r] = p;
        lsum += p;
      }
    }
    // ---- P: pack to bf16 pairs, then quad-permute into A-frag layout ----
    // A-frag key quad*8+j <- lane ((quad&1)*2+(j>>2))*16+lo16, group quad>>1, r=j&3
    int pkl[4], pkh[4];
#pragma unroll
    for (int gg = 0; gg < 4; gg++) {
      union { bf16x4 h; int2 i; } u;
      u.h[0] = (__bf16)s[gg][0]; u.h[1] = (__bf16)s[gg][1];
      u.h[2] = (__bf16)s[gg][2]; u.h[3] = (__bf16)s[gg][3];
      pkl[gg] = u.i.x; pkh[gg] = u.i.y;
    }
    const int S0 = (quad & 1) * 32 + lo16;
    const int S1 = S0 + 16;
    const bool hiq = quad >= 2;
    union { int4 i; bf16x8 h; } w0, w1;
    {
      int x0 = __shfl(pkl[0], S0, 64), x1 = __shfl(pkh[0], S0, 64);
      int x2 = __shfl(pkl[0], S1, 64), x3 = __shfl(pkh[0], S1, 64);
      int y0 = __shfl(pkl[1], S0, 64), y1 = __shfl(pkh[1], S0, 64);
      int y2 = __shfl(pkl[1], S1, 64), y3 = __shfl(pkh[1], S1, 64);
      w0.i = make_int4(hiq ? y0 : x0, hiq ? y1 : x1, hiq ? y2 : x2, hiq ? y3 : x3);
    }
    {
      int x0 = __shfl(pkl[2], S0, 64), x1 = __shfl(pkh[2], S0, 64);
      int x2 = __shfl(pkl[2], S1, 64), x3 = __shfl(pkh[2], S1, 64);
      int y0 = __shfl(pkl[3], S0, 64), y1 = __shfl(pkh[3], S0, 64);
      int y2 = __shfl(pkl[3], S1, 64), y3 = __shfl(pkh[3], S1, 64);
      w1.i = make_int4(hiq ? y0 : x0, hiq ? y1 : x1, hiq ? y2 : x2, hiq ? y3 : x3);
    }
    bf16x8 a_p0 = w0.h;  // keys 0..31  (k=quad*8+j)
    bf16x8 a_p1 = w1.h;  // keys 32..63
    // ---- O_v += P V, O_k += P K ----
#pragma unroll
    for (int gg = 0; gg < 4; gg++) {
      int row = gg * 16 + lo16;  // d row in vt/kt bufs
      bf16x8 bv0 = *(const bf16x8*)(&vtbuf[cur][row * 64 + ((quad ^ rsw) * 8)]);
      bf16x8 bv1 = *(const bf16x8*)(&vtbuf[cur][row * 64 + (((quad + 4) ^ rsw) * 8)]);
      acc_v[gg] = __builtin_amdgcn_mfma_f32_16x16x32_bf16(a_p0, bv0, acc_v[gg], 0, 0, 0);
      acc_v[gg] = __builtin_amdgcn_mfma_f32_16x16x32_bf16(a_p1, bv1, acc_v[gg], 0, 0, 0);
      bf16x8 bk0 = *(const bf16x8*)(&ktbuf[cur][row * 64 + ((quad ^ rsw) * 8)]);
      bf16x8 bk1 = *(const bf16x8*)(&ktbuf[cur][row * 64 + (((quad + 4) ^ rsw) * 8)]);
      acc_k[gg] = __builtin_amdgcn_mfma_f32_16x16x32_bf16(a_p0, bk0, acc_k[gg], 0, 0, 0);
      acc_k[gg] = __builtin_amdgcn_mfma_f32_16x16x32_bf16(a_p1, bk1, acc_k[gg], 0, 0, 0);
    }
  }

  // row sums: lane holds partial for q=lo16; reduce across quads, then
  // redistribute to output-row ownership (q = quad*4+r).
  lsum += __shfl_xor(lsum, 16, 64);
  lsum += __shfl_xor(lsum, 32, 64);
  float inv_l[4];
#pragma unroll
  for (int r = 0; r < 4; r++) inv_l[r] = 1.0f / __shfl(lsum, quad * 4 + r, 64);

  size_t obase = ((size_t)b * LQ_ + q0 + quad * 4) * DM_ + h * DH_;
#pragma unroll
  for (int gg = 0; gg < 4; gg++) {
#pragma unroll
    for (int r = 0; r < 4; r++) {
      size_t idx = obase + (size_t)r * DM_ + gg * 16 + lo16;
      out_k[idx] = acc_k[gg][r] * inv_l[r];
      out_v[idx] = acc_v[gg][r] * inv_l[r];
    }
  }
}

extern "C" void kernel_launch(void* const* d_in, const int* in_sizes, int n_in,
                              void* d_out, int out_size, void* d_ws, size_t ws_size,
                              hipStream_t stream) {
  const float* q = (const float*)d_in[0];
  const float* k = (const float*)d_in[1];
  const float* v = (const float*)d_in[2];
  const int* mask = (const int*)d_in[3];
  const float* Wq = (const float*)d_in[4];
  const float* bq = (const float*)d_in[5];
  const float* Wk = (const float*)d_in[6];
  const float* bk = (const float*)d_in[7];
  const float* Wv = (const float*)d_in[8];
  const float* bv = (const float*)d_in[9];
  float* out = (float*)d_out;

  // ws: qh | kh | khTt | vhTt (bf16, 8.4MB ea) | maskp (1MB)  -> ~34.6 MB
  const size_t HTOT = (size_t)B_ * NH_ * LQ_ * DH_;
  const size_t XTOT = (size_t)B_ * LQ_ * DM_;
  __bf16* qh = (__bf16*)d_ws;
  __bf16* kh = qh + HTOT;
  __bf16* khT = kh + HTOT;
  __bf16* vhT = khT + HTOT;
  unsigned* maskp = (unsigned*)(vhT + HTOT);

  // bf16 X/W scratch lives in d_out (dead before attn writes the outputs).
  __bf16* X0 = (__bf16*)d_out;
  __bf16* X1 = X0 + XTOT;
  __bf16* X2 = X1 + XTOT;
  __bf16* W0 = X2 + XTOT;
  __bf16* W1 = W0 + (size_t)DM_ * DM_;
  __bf16* W2 = W1 + (size_t)DM_ * DM_;

  pack_mask_kernel<<<(B_ * LQ_ * LK_) / 256, 256, 0, stream>>>(mask, maskp);
  cvt6_kernel<<<dim3(XTOT / 1024, 6), 256, 0, stream>>>(
      q, k, v, Wq, Wk, Wv, X0, X1, X2, W0, W1, W2);
  proj_kernel<<<dim3(32, 8, 3), 256, 0, stream>>>(
      X0, X1, X2, bq, bk, bv, W0, W1, W2, qh, kh, khT, vhT);
  attn_kernel<<<dim3(32, 32), 256, 0, stream>>>(qh, kh, khT, vhT, maskp,
                                                out, out + (size_t)B_ * LQ_ * DM_);
}

// Round 7
// 280.436 us; speedup vs baseline: 1.0457x; 1.0457x over previous
//
#include <hip/hip_runtime.h>
#include <hip/hip_bf16.h>
#include <stdint.h>

typedef __bf16 bf16x8 __attribute__((ext_vector_type(8)));
typedef __bf16 bf16x4 __attribute__((ext_vector_type(4)));
typedef float f32x4 __attribute__((ext_vector_type(4)));

#define B_ 2
#define LQ_ 2048
#define LK_ 2048
#define NH_ 16
#define DH_ 64
#define DM_ 1024
#define NKT_ (LK_ / 64)

#define AS1 __attribute__((address_space(1)))
#define AS3 __attribute__((address_space(3)))

__device__ __forceinline__ void gload_lds16(const void* g, void* l) {
  __builtin_amdgcn_global_load_lds((const AS1 uint32_t*)g, (AS3 uint32_t*)l, 16, 0, 0);
}

// Fused prep: blocks [0,960) convert q,k,v,Wq,Wk,Wv fp32 -> bf16 in k-tiled
// layout T[kt][row][32] (chunk c' stores true chunk c'^(row&3) so proj's LDS
// frag reads land conflict-spread); blocks [960,9152) pack the mask to bits.
__global__ __launch_bounds__(256) void prep_kernel(
    const float* __restrict__ q, const float* __restrict__ k,
    const float* __restrict__ v, const float* __restrict__ wq,
    const float* __restrict__ wk, const float* __restrict__ wv,
    const int* __restrict__ mask,
    __bf16* __restrict__ Xt0, __bf16* __restrict__ Xt1, __bf16* __restrict__ Xt2,
    __bf16* __restrict__ Wt0, __bf16* __restrict__ Wt1, __bf16* __restrict__ Wt2,
    unsigned* __restrict__ maskp) {
  const int t = threadIdx.x;
  const int bidx = blockIdx.x;
  if (bidx >= 960) {
    // ---- mask pack: thread covers 4 ints; nibble OR-reduce over 8 lanes ----
    int pb = bidx - 960;
    int lane = t & 63;
    size_t gi = ((size_t)pb * 256 + t) * 4;
    int4 mv = *(const int4*)(mask + gi);
    unsigned nib = (mv.x != 0 ? 1u : 0u) | (mv.y != 0 ? 2u : 0u) |
                   (mv.z != 0 ? 4u : 0u) | (mv.w != 0 ? 8u : 0u);
    unsigned vv = nib << ((lane & 7) * 4);
    vv |= __shfl_xor(vv, 1, 64);
    vv |= __shfl_xor(vv, 2, 64);
    vv |= __shfl_xor(vv, 4, 64);
    if ((lane & 7) == 0) maskp[gi >> 5] = vv;
    return;
  }
  // ---- cvt: 16 source rows x 1024 k through LDS transpose ----
  __shared__ __align__(16) __bf16 lb[16][1032];
  const float* src; __bf16* dst; int rows, m0;
  if (bidx < 256)      { src = q;  dst = Xt0; rows = 4096; m0 = bidx * 16; }
  else if (bidx < 512) { src = k;  dst = Xt1; rows = 4096; m0 = (bidx - 256) * 16; }
  else if (bidx < 768) { src = v;  dst = Xt2; rows = 4096; m0 = (bidx - 512) * 16; }
  else if (bidx < 832) { src = wq; dst = Wt0; rows = 1024; m0 = (bidx - 768) * 16; }
  else if (bidx < 896) { src = wk; dst = Wt1; rows = 1024; m0 = (bidx - 832) * 16; }
  else                 { src = wv; dst = Wt2; rows = 1024; m0 = (bidx - 896) * 16; }
#pragma unroll
  for (int i = 0; i < 16; i++) {
    float4 f = *(const float4*)(src + (size_t)(m0 + i) * DM_ + t * 4);
    bf16x4 o;
    o[0] = (__bf16)f.x; o[1] = (__bf16)f.y; o[2] = (__bf16)f.z; o[3] = (__bf16)f.w;
    *(bf16x4*)&lb[i][t * 4] = o;
  }
  __syncthreads();
  const int wave = t >> 6, lane = t & 63;
  const int m = lane >> 2, c = lane & 3;
#pragma unroll
  for (int j = 0; j < 8; j++) {
    int kt = wave * 8 + j;
    bf16x8 val = *(const bf16x8*)&lb[m][kt * 32 + (c ^ (m & 3)) * 8];
    *(bf16x8*)(dst + ((size_t)kt * rows + m0 + m) * 32 + c * 8) = val;  // 1KB/instr
  }
}

// GEMM C = X @ W^T + bias, 128x128 tile, BK=32, double-buffered staging from
// k-tiled inputs: each global_load_lds covers one contiguous 1KB span.
// mode=blockIdx.z: 0=q(std), 1=k(std+T), 2=v(T). T out: T[bh][kti][d][64].
__global__ __launch_bounds__(256) void proj_kernel(
    const __bf16* __restrict__ Xt0, const __bf16* __restrict__ Xt1,
    const __bf16* __restrict__ Xt2,
    const float* __restrict__ b0p, const float* __restrict__ b1p,
    const float* __restrict__ b2p,
    const __bf16* __restrict__ Wt0, const __bf16* __restrict__ Wt1,
    const __bf16* __restrict__ Wt2,
    __bf16* __restrict__ qh, __bf16* __restrict__ kh,
    __bf16* __restrict__ khT, __bf16* __restrict__ vhT) {
  __shared__ __align__(16) __bf16 smem[2][2][128 * 32];
  __bf16* cbuf = &smem[0][0][0];  // epilogue alias (18 KB < 32 KB)

  const int mode = blockIdx.z;
  const __bf16* Xt = mode == 0 ? Xt0 : (mode == 1 ? Xt1 : Xt2);
  const __bf16* Wt = mode == 0 ? Wt0 : (mode == 1 ? Wt1 : Wt2);
  const float* bias = mode == 0 ? b0p : (mode == 1 ? b1p : b2p);
  __bf16* ostd = mode == 0 ? qh : (mode == 1 ? kh : nullptr);
  __bf16* otr = mode == 0 ? nullptr : (mode == 1 ? khT : vhT);

  const int t = threadIdx.x;
  const int wave = t >> 6, lane = t & 63;
  const int lo16 = lane & 15, quad = lane >> 4;
  const int wm = wave >> 1, wn = wave & 1;
  const int m0 = blockIdx.x * 128, n0 = blockIdx.y * 128;

  f32x4 acc[4][4] = {};

  auto stage = [&](int kt, int sel) {
#pragma unroll
    for (int ii = 2 * wave; ii < 2 * wave + 2; ii++) {
      gload_lds16(Xt + ((size_t)kt * 4096 + m0 + ii * 16) * 32 + lane * 8,
                  &smem[sel][0][ii * 512]);
      gload_lds16(Wt + ((size_t)kt * 1024 + n0 + ii * 16) * 32 + lane * 8,
                  &smem[sel][1][ii * 512]);
    }
  };

  stage(0, 0);
  for (int kt = 0; kt < 32; kt++) {
    const int sel = kt & 1;
    __syncthreads();
    if (kt + 1 < 32) stage(kt + 1, sel ^ 1);
    bf16x8 af[4], bfr[4];
#pragma unroll
    for (int g = 0; g < 4; g++) {
      int ar = wm * 64 + g * 16 + lo16;
      af[g] = *(const bf16x8*)(&smem[sel][0][ar * 32 + (quad ^ (ar & 3)) * 8]);
      int br = wn * 64 + g * 16 + lo16;
      bfr[g] = *(const bf16x8*)(&smem[sel][1][br * 32 + (quad ^ (br & 3)) * 8]);
    }
#pragma unroll
    for (int gm = 0; gm < 4; gm++)
#pragma unroll
      for (int gn = 0; gn < 4; gn++)
        acc[gm][gn] =
            __builtin_amdgcn_mfma_f32_16x16x32_bf16(af[gm], bfr[gn], acc[gm][gn], 0, 0, 0);
  }

  const int b = m0 >> 11, l0 = m0 & 2047;
  for (int nhf = 0; nhf < 2; nhf++) {
    int h = (n0 >> 6) + nhf;
    int bh = b * NH_ + h;
    if (ostd) {
      __syncthreads();
      if (wn == nhf) {
#pragma unroll
        for (int gn = 0; gn < 4; gn++) {
          float bi = bias[n0 + nhf * 64 + gn * 16 + lo16];
#pragma unroll
          for (int gm = 0; gm < 4; gm++)
#pragma unroll
            for (int r = 0; r < 4; r++)
              cbuf[(wm * 64 + gm * 16 + quad * 4 + r) * 72 + gn * 16 + lo16] =
                  (__bf16)(acc[gm][gn][r] + bi);
        }
      }
      __syncthreads();
      int m = t >> 1, coff = (t & 1) * 32;
      __bf16* dst = ostd + ((size_t)bh * LQ_ + l0 + m) * DH_ + coff;
#pragma unroll
      for (int j = 0; j < 4; j++)
        *(bf16x8*)(dst + j * 8) = *(const bf16x8*)&cbuf[m * 72 + coff + j * 8];
    }
    if (otr) {
      __syncthreads();
      if (wn == nhf) {
#pragma unroll
        for (int gn = 0; gn < 4; gn++) {
          float bi = bias[n0 + nhf * 64 + gn * 16 + lo16];
#pragma unroll
          for (int gm = 0; gm < 4; gm++) {
            bf16x4 pk;
#pragma unroll
            for (int r = 0; r < 4; r++) pk[r] = (__bf16)(acc[gm][gn][r] + bi);
            *(bf16x4*)&cbuf[(gn * 16 + lo16) * 136 + wm * 64 + gm * 16 + quad * 4] = pk;
          }
        }
      }
      __syncthreads();
      int d = t >> 2, mc = (t & 3) * 32;
      int kti = (l0 + mc) >> 6, kl = (l0 + mc) & 63;
      __bf16* dst = otr + ((size_t)(bh * NKT_ + kti) * 64 + d) * 64 + kl;
#pragma unroll
      for (int j = 0; j < 4; j++)
        *(bf16x8*)(dst + j * 8) = *(const bf16x8*)&cbuf[d * 136 + mc + j * 8];
    }
  }
}

// Flash attention (R5 structure, verbatim): LDS-staged K/KT/VT tiles,
// double-buffered, 128 q-rows per block, one barrier/tile, fixed-max softmax,
// P via wave-private LDS round-trip. blockIdx.x = bh -> XCD L2 locality.
__global__ __launch_bounds__(256) void attn_kernel(
    const __bf16* __restrict__ qh, const __bf16* __restrict__ kh,
    const __bf16* __restrict__ khT, const __bf16* __restrict__ vhT,
    const unsigned* __restrict__ maskp,
    float* __restrict__ out_k, float* __restrict__ out_v) {
  __shared__ __align__(16) __bf16 kbuf[2][64 * 64];
  __shared__ __align__(16) __bf16 ktbuf[2][64 * 64];
  __shared__ __align__(16) __bf16 vtbuf[2][64 * 64];
  __shared__ __align__(16) __bf16 p_lds[4][2][16][72];

  const int t = threadIdx.x;
  const int wave = t >> 6, lane = t & 63;
  const int lo16 = lane & 15, quad = lane >> 4;
  const int bh = blockIdx.x;
  const int b = bh >> 4, h = bh & 15;
  const int q0 = blockIdx.y * 128 + wave * 16;  // group g adds g*64
  const int srow = lane >> 3;
  const int scg = (lane & 7) ^ srow;  // XOR chunk swizzle
  const int rsw = lo16 & 7;           // read-side row & 7

  bf16x8 a_q0[2], a_q1[2];
#pragma unroll
  for (int g = 0; g < 2; g++) {
    const __bf16* qrow = qh + ((size_t)bh * LQ_ + q0 + g * 64 + lo16) * DH_ + quad * 8;
    a_q0[g] = *(const bf16x8*)(qrow);
    a_q1[g] = *(const bf16x8*)(qrow + 32);
  }

  f32x4 acc_v[2][4] = {};
  f32x4 acc_k[2][4] = {};
  float lsum[2][4] = {};

  const __bf16* khb = kh + (size_t)bh * LK_ * DH_;
  const __bf16* ktb = khT + (size_t)bh * LK_ * DH_;
  const __bf16* vtb = vhT + (size_t)bh * LK_ * DH_;

  auto stage = [&](int kti, int sel) {
    const int tb = kti * 4096;
#pragma unroll
    for (int ii = 2 * wave; ii < 2 * wave + 2; ii++) {
      int row = ii * 8 + srow;
      gload_lds16(khb + (size_t)(kti * 64 + row) * DH_ + scg * 8, &kbuf[sel][ii * 512]);
      gload_lds16(ktb + tb + row * 64 + scg * 8, &ktbuf[sel][ii * 512]);
      gload_lds16(vtb + tb + row * 64 + scg * 8, &vtbuf[sel][ii * 512]);
    }
  };

  stage(0, 0);
  for (int kti = 0; kti < NKT_; kti++) {
    const int cur = kti & 1;
    __syncthreads();  // drains stage(cur), issued a full compute-phase ago
    if (kti + 1 < NKT_) stage(kti + 1, cur ^ 1);
#pragma unroll
    for (int g = 0; g < 2; g++) {
      // ---- S = Q K^T ----
      f32x4 s[4];
#pragma unroll
      for (int gg = 0; gg < 4; gg++) {
        int row = gg * 16 + lo16;
        bf16x8 kb0 = *(const bf16x8*)(&kbuf[cur][row * 64 + ((quad ^ rsw) * 8)]);
        bf16x8 kb1 = *(const bf16x8*)(&kbuf[cur][row * 64 + (((quad + 4) ^ rsw) * 8)]);
        f32x4 z = {};
        z = __builtin_amdgcn_mfma_f32_16x16x32_bf16(a_q0[g], kb0, z, 0, 0, 0);
        z = __builtin_amdgcn_mfma_f32_16x16x32_bf16(a_q1[g], kb1, z, 0, 0, 0);
        s[gg] = z;
      }
      // ---- mask + exp (fixed max = 0) ----
      const unsigned* mb =
          maskp + ((size_t)b * LQ_ + q0 + g * 64 + quad * 4) * (LK_ / 32);
      unsigned mw0[4], mw1[4];
#pragma unroll
      for (int r = 0; r < 4; r++) {
        mw0[r] = mb[r * (LK_ / 32) + kti * 2];
        mw1[r] = mb[r * (LK_ / 32) + kti * 2 + 1];
      }
#pragma unroll
      for (int gg = 0; gg < 4; gg++) {
        int bitpos = (gg * 16 + lo16) & 31;
#pragma unroll
        for (int r = 0; r < 4; r++) {
          unsigned w = (gg >= 2) ? mw1[r] : mw0[r];
          float arg = ((w >> bitpos) & 1) ? s[gg][r] * 0.125f : -28.0f;
          float p = __expf(arg);
          s[gg][r] = p;
          lsum[g][r] += p;
        }
      }
      // ---- P: C-layout regs -> LDS -> A-layout frags (wave-private) ----
#pragma unroll
      for (int gg = 0; gg < 4; gg++) {
#pragma unroll
        for (int r = 0; r < 4; r++)
          p_lds[wave][g][quad * 4 + r][gg * 16 + lo16] = (__bf16)s[gg][r];
      }
      bf16x8 a_p0 = *(const bf16x8*)&p_lds[wave][g][lo16][quad * 8];
      bf16x8 a_p1 = *(const bf16x8*)&p_lds[wave][g][lo16][32 + quad * 8];
      // ---- O_v += P V, O_k += P K ----
#pragma unroll
      for (int gg = 0; gg < 4; gg++) {
        int row = gg * 16 + lo16;
        bf16x8 bv0 = *(const bf16x8*)(&vtbuf[cur][row * 64 + ((quad ^ rsw) * 8)]);
        bf16x8 bv1 = *(const bf16x8*)(&vtbuf[cur][row * 64 + (((quad + 4) ^ rsw) * 8)]);
        acc_v[g][gg] = __builtin_amdgcn_mfma_f32_16x16x32_bf16(a_p0, bv0, acc_v[g][gg], 0, 0, 0);
        acc_v[g][gg] = __builtin_amdgcn_mfma_f32_16x16x32_bf16(a_p1, bv1, acc_v[g][gg], 0, 0, 0);
        bf16x8 bk0 = *(const bf16x8*)(&ktbuf[cur][row * 64 + ((quad ^ rsw) * 8)]);
        bf16x8 bk1 = *(const bf16x8*)(&ktbuf[cur][row * 64 + (((quad + 4) ^ rsw) * 8)]);
        acc_k[g][gg] = __builtin_amdgcn_mfma_f32_16x16x32_bf16(a_p0, bk0, acc_k[g][gg], 0, 0, 0);
        acc_k[g][gg] = __builtin_amdgcn_mfma_f32_16x16x32_bf16(a_p1, bk1, acc_k[g][gg], 0, 0, 0);
      }
    }
  }

#pragma unroll
  for (int off = 1; off < 16; off <<= 1) {
#pragma unroll
    for (int g = 0; g < 2; g++)
#pragma unroll
      for (int r = 0; r < 4; r++) lsum[g][r] += __shfl_xor(lsum[g][r], off, 64);
  }
#pragma unroll
  for (int g = 0; g < 2; g++) {
    float inv_l[4];
#pragma unroll
    for (int r = 0; r < 4; r++) inv_l[r] = 1.0f / lsum[g][r];
    size_t obase = ((size_t)b * LQ_ + q0 + g * 64 + quad * 4) * DM_ + h * DH_;
#pragma unroll
    for (int gg = 0; gg < 4; gg++) {
#pragma unroll
      for (int r = 0; r < 4; r++) {
        size_t idx = obase + (size_t)r * DM_ + gg * 16 + lo16;
        out_k[idx] = acc_k[g][gg][r] * inv_l[r];
        out_v[idx] = acc_v[g][gg][r] * inv_l[r];
      }
    }
  }
}

extern "C" void kernel_launch(void* const* d_in, const int* in_sizes, int n_in,
                              void* d_out, int out_size, void* d_ws, size_t ws_size,
                              hipStream_t stream) {
  const float* q = (const float*)d_in[0];
  const float* k = (const float*)d_in[1];
  const float* v = (const float*)d_in[2];
  const int* mask = (const int*)d_in[3];
  const float* Wq = (const float*)d_in[4];
  const float* bq = (const float*)d_in[5];
  const float* Wk = (const float*)d_in[6];
  const float* bk = (const float*)d_in[7];
  const float* Wv = (const float*)d_in[8];
  const float* bv = (const float*)d_in[9];
  float* out = (float*)d_out;

  // ws: qh | kh | khTt | vhTt (bf16, 8.4MB ea) | maskp (1MB)
  const size_t HTOT = (size_t)B_ * NH_ * LQ_ * DH_;
  const size_t XTOT = (size_t)B_ * LQ_ * DM_;
  __bf16* qh = (__bf16*)d_ws;
  __bf16* kh = qh + HTOT;
  __bf16* khT = kh + HTOT;
  __bf16* vhT = khT + HTOT;
  unsigned* maskp = (unsigned*)(vhT + HTOT);

  // k-tiled bf16 X/W scratch lives in d_out (dead before attn writes outputs):
  // 3*8.4 + 3*2.1 = 31.5 MB <= 33.5 MB.
  __bf16* Xt0 = (__bf16*)d_out;
  __bf16* Xt1 = Xt0 + XTOT;
  __bf16* Xt2 = Xt1 + XTOT;
  __bf16* Wt0 = Xt2 + XTOT;
  __bf16* Wt1 = Wt0 + (size_t)DM_ * DM_;
  __bf16* Wt2 = Wt1 + (size_t)DM_ * DM_;

  prep_kernel<<<960 + 8192, 256, 0, stream>>>(
      q, k, v, Wq, Wk, Wv, mask, Xt0, Xt1, Xt2, Wt0, Wt1, Wt2, maskp);
  proj_kernel<<<dim3(32, 8, 3), 256, 0, stream>>>(
      Xt0, Xt1, Xt2, bq, bk, bv, Wt0, Wt1, Wt2, qh, kh, khT, vhT);
  attn_kernel<<<dim3(32, 16), 256, 0, stream>>>(qh, kh, khT, vhT, maskp,
                                                out, out + (size_t)B_ * LQ_ * DM_);
}